// Round 1
// baseline (43756.049 us; speedup 1.0000x reference)
//
#include <hip/hip_runtime.h>

#define TAPS 81   // 3^4
#define D3TILE 4

// Direct fp32 4D conv, stride 1, pad 1, fused bias+ReLU.
// Block: 256 threads = 16 d4-lanes x 16 co-lanes. Each block computes
// out[b, :, d1, d2, d3b:d3b+4, :]  (Cout x 4 x 16 values).
// Weights for one ci (Cout*81 floats) staged in LDS per ci-iteration.
template<int CIN, int COUT>
__global__ __launch_bounds__(256) void conv4d_layer(
    const float* __restrict__ in, const float* __restrict__ w,
    const float* __restrict__ bias, float* __restrict__ out)
{
    constexpr int CO_PER = (COUT + 15) / 16;
    __shared__ float ws[COUT * TAPS];

    const int tid = threadIdx.x;
    const int d4 = tid & 15;
    const int colane = tid >> 4;

    int idx = blockIdx.x;
    const int d3grp = idx & 3; idx >>= 2;
    const int d2 = idx & 15; idx >>= 4;
    const int d1 = idx & 15; idx >>= 4;
    const int b = idx;
    const int d3b = d3grp * D3TILE;

    float acc[D3TILE][CO_PER];
    #pragma unroll
    for (int r = 0; r < D3TILE; ++r)
        #pragma unroll
        for (int c = 0; c < CO_PER; ++c) acc[r][c] = 0.f;

    for (int ci = 0; ci < CIN; ++ci) {
        // stage w[co][ci][t] -> ws[co*81 + t]
        for (int i = tid; i < COUT * TAPS; i += 256) {
            int co = i / TAPS, t = i - co * TAPS;
            ws[i] = w[(co * CIN + ci) * TAPS + t];
        }
        __syncthreads();

        const float* inb = in + (size_t)(b * CIN + ci) * (16 * 16 * 16 * 16);

        for (int t1 = 0; t1 < 3; ++t1) {
            const int e1 = d1 + t1 - 1;
            const bool v1 = (unsigned)e1 < 16u;
            for (int t2 = 0; t2 < 3; ++t2) {
                const int e2 = d2 + t2 - 1;
                const bool v12 = v1 && ((unsigned)e2 < 16u);
                #pragma unroll
                for (int t3 = 0; t3 < 3; ++t3) {
                    float xv[D3TILE][3];
                    #pragma unroll
                    for (int r = 0; r < D3TILE; ++r) {
                        const int e3 = d3b + r + t3 - 1;
                        const bool v = v12 && ((unsigned)e3 < 16u);
                        const float* row = inb + (((e1 * 16 + e2) * 16 + e3) * 16);
                        xv[r][0] = (v && d4 > 0)  ? row[d4 - 1] : 0.f;
                        xv[r][1] = v              ? row[d4]     : 0.f;
                        xv[r][2] = (v && d4 < 15) ? row[d4 + 1] : 0.f;
                    }
                    const int tb = ((t1 * 3 + t2) * 3 + t3) * 3;
                    #pragma unroll
                    for (int c = 0; c < CO_PER; ++c) {
                        const int co = colane + c * 16;
                        float w0 = 0.f, w1 = 0.f, w2 = 0.f;
                        if (co < COUT) {
                            w0 = ws[co * TAPS + tb + 0];
                            w1 = ws[co * TAPS + tb + 1];
                            w2 = ws[co * TAPS + tb + 2];
                        }
                        #pragma unroll
                        for (int r = 0; r < D3TILE; ++r) {
                            acc[r][c] += w0 * xv[r][0] + w1 * xv[r][1] + w2 * xv[r][2];
                        }
                    }
                }
            }
        }
        __syncthreads();
    }

    // epilogue: bias + ReLU (all 6 layers end in ReLU per reference)
    #pragma unroll
    for (int c = 0; c < CO_PER; ++c) {
        const int co = colane + c * 16;
        if (co < COUT) {
            const float bv = bias[co];
            #pragma unroll
            for (int r = 0; r < D3TILE; ++r) {
                float v = acc[r][c] + bv;
                v = v > 0.f ? v : 0.f;
                out[(((((size_t)b * COUT + co) * 16 + d1) * 16 + d2) * 16 + (d3b + r)) * 16 + d4] = v;
            }
        }
    }
}

extern "C" void kernel_launch(void* const* d_in, const int* in_sizes, int n_in,
                              void* d_out, int out_size, void* d_ws, size_t ws_size,
                              hipStream_t stream) {
    const float* x  = (const float*)d_in[0];
    const float* w1 = (const float*)d_in[1];  const float* b1 = (const float*)d_in[2];
    const float* w2 = (const float*)d_in[3];  const float* b2 = (const float*)d_in[4];
    const float* w3 = (const float*)d_in[5];  const float* b3 = (const float*)d_in[6];
    const float* w4 = (const float*)d_in[7];  const float* b4 = (const float*)d_in[8];
    const float* w5 = (const float*)d_in[9];  const float* b5 = (const float*)d_in[10];
    const float* w6 = (const float*)d_in[11]; const float* b6 = (const float*)d_in[12];

    // ping-pong activation buffers in workspace (fp32):
    // buf0 holds layer 1/3/5 outputs (max 160 ch = 83.9 MB)
    // buf1 holds layer 2/4 outputs   (max  80 ch = 41.9 MB)
    float* buf0 = (float*)d_ws;
    float* buf1 = buf0 + (size_t)2 * 160 * 65536;

    const dim3 grid(2 * 16 * 16 * (16 / D3TILE));
    const dim3 block(256);

    conv4d_layer<1,   40><<<grid, block, 0, stream>>>(x,    w1, b1, buf0);
    conv4d_layer<40,  80><<<grid, block, 0, stream>>>(buf0, w2, b2, buf1);
    conv4d_layer<80, 160><<<grid, block, 0, stream>>>(buf1, w3, b3, buf0);
    conv4d_layer<160, 80><<<grid, block, 0, stream>>>(buf0, w4, b4, buf1);
    conv4d_layer<80,  40><<<grid, block, 0, stream>>>(buf1, w5, b5, buf0);
    conv4d_layer<40,   1><<<grid, block, 0, stream>>>(buf0, w6, b6, (float*)d_out);
}

// Round 2
// 1833.761 us; speedup vs baseline: 23.8614x; 23.8614x over previous
//
#include <hip/hip_runtime.h>

typedef __attribute__((ext_vector_type(8))) short short8;
typedef __attribute__((ext_vector_type(4))) float f32x4;

__device__ __forceinline__ ushort f2bf(float f){
    union { float f; unsigned u; } v; v.f = f;
    unsigned r = (v.u + 0x7fffu + ((v.u >> 16) & 1u)) >> 16;
    return (ushort)r;
}
__device__ __forceinline__ float bf2f(ushort u){
    union { unsigned u; float f; } v; v.u = ((unsigned)u) << 16;
    return v.f;
}

// ---------------- Layer 1: Cin=1 -> 40 real (stored 64, pad zero), direct fp32 ----------
__global__ __launch_bounds__(256) void conv_l1(
    const float* __restrict__ x, const float* __restrict__ w,
    const float* __restrict__ bias, ushort* __restrict__ out)
{
    __shared__ float xs[2916];     // [3][3][18][18] padded neighborhood
    __shared__ float wsh[3240];    // [40][81]
    const int tid = threadIdx.x;
    const int bx = blockIdx.x;
    const int d2 = bx & 15, d1 = (bx >> 4) & 15, b = bx >> 8;
    const float* xb = x + (size_t)b * 65536;

    for (int i = tid; i < 2916; i += 256){
        int i4 = i % 18; int r1 = i / 18; int i3 = r1 % 18;
        int r2 = r1 / 18; int a2 = r2 % 3; int a1 = r2 / 3;
        int e1 = d1 + a1 - 1, e2 = d2 + a2 - 1, e3 = i3 - 1, e4 = i4 - 1;
        float v = 0.f;
        if ((unsigned)e1 < 16u && (unsigned)e2 < 16u && (unsigned)e3 < 16u && (unsigned)e4 < 16u)
            v = xb[((e1 * 16 + e2) * 16 + e3) * 16 + e4];
        xs[i] = v;
    }
    for (int i = tid; i < 3240; i += 256) wsh[i] = w[i];
    __syncthreads();

    const int d3 = tid >> 4, d4 = tid & 15;
    float acc[40];
    #pragma unroll
    for (int c = 0; c < 40; ++c) acc[c] = 0.f;

    for (int t1 = 0; t1 < 3; ++t1)
    for (int t2 = 0; t2 < 3; ++t2)
    for (int t3 = 0; t3 < 3; ++t3)
    #pragma unroll
    for (int t4 = 0; t4 < 3; ++t4){
        float xv = xs[((t1 * 3 + t2) * 18 + d3 + t3) * 18 + d4 + t4];
        int tap = ((t1 * 3 + t2) * 3 + t3) * 3 + t4;
        #pragma unroll
        for (int c = 0; c < 40; ++c) acc[c] += wsh[c * 81 + tap] * xv;
    }

    ushort* ob = out + ((size_t)bx * 256 + tid) * 64;
    #pragma unroll
    for (int c = 0; c < 40; ++c){
        float v = acc[c] + bias[c]; v = v > 0.f ? v : 0.f;
        ob[c] = f2bf(v);
    }
    #pragma unroll
    for (int c = 40; c < 64; ++c) ob[c] = 0;
}

// ---------------- Layer 6: 40 real (stored 64) -> Cout=1, direct fp32 -------------------
__global__ __launch_bounds__(256) void conv_l6(
    const ushort* __restrict__ in, const float* __restrict__ w,
    const float* __restrict__ bias, float* __restrict__ out)
{
    __shared__ float wsh[3240];    // [ci=40][81]
    const int tid = threadIdx.x;
    const int bx = blockIdx.x;
    const int d2 = bx & 15, d1 = (bx >> 4) & 15, b = bx >> 8;
    for (int i = tid; i < 3240; i += 256) wsh[i] = w[i];
    __syncthreads();

    const int d3 = tid >> 4, d4 = tid & 15;
    const ushort* inb = in + (size_t)b * 65536 * 64;
    float acc = 0.f;
    for (int t1 = 0; t1 < 3; ++t1){
        int e1 = d1 + t1 - 1; if ((unsigned)e1 >= 16u) continue;
        for (int t2 = 0; t2 < 3; ++t2){
            int e2 = d2 + t2 - 1; if ((unsigned)e2 >= 16u) continue;
            for (int t3 = 0; t3 < 3; ++t3){
                int e3 = d3 + t3 - 1; if ((unsigned)e3 >= 16u) continue;
                for (int t4 = 0; t4 < 3; ++t4){
                    int e4 = d4 + t4 - 1; if ((unsigned)e4 >= 16u) continue;
                    const ushort* p = inb + (size_t)(((e1 * 16 + e2) * 16 + e3) * 16 + e4) * 64;
                    int tap = ((t1 * 3 + t2) * 3 + t3) * 3 + t4;
                    #pragma unroll
                    for (int c8 = 0; c8 < 5; ++c8){
                        short8 v = *(const short8*)(p + c8 * 8);
                        #pragma unroll
                        for (int j = 0; j < 8; ++j)
                            acc += bf2f((ushort)v[j]) * wsh[(c8 * 8 + j) * 81 + tap];
                    }
                }
            }
        }
    }
    float v = acc + bias[0]; v = v > 0.f ? v : 0.f;
    out[(size_t)bx * 256 + tid] = v;
}

// ---------------- Weight repack: [co][ci][81] fp32 -> [81][ci/8][co][8] bf16 ------------
__global__ void repack_w(const float* __restrict__ w, ushort* __restrict__ wp,
                         int cin, int cout, int cin_s, int cout_c)
{
    const int total = 81 * cin_s * cout_c;
    for (int i = blockIdx.x * blockDim.x + threadIdx.x; i < total; i += gridDim.x * blockDim.x){
        int j = i & 7;
        int rest = i >> 3;
        int co = rest % cout_c;
        int rest2 = rest / cout_c;
        int ci_hi = rest2 % (cin_s >> 3);
        int t = rest2 / (cin_s >> 3);
        int ci = ci_hi * 8 + j;
        float v = (ci < cin && co < cout) ? w[((size_t)co * cin + ci) * 81 + t] : 0.f;
        wp[i] = f2bf(v);
    }
}

// ---------------- Zero-fill pad channels 80..95 of a [131072][96] buffer ---------------
__global__ void fill_pad(ushort* __restrict__ buf){
    int i = blockIdx.x * blockDim.x + threadIdx.x;   // 131072*16 threads
    if (i < 131072 * 16){
        int pos = i >> 4, c = 80 + (i & 15);
        buf[(size_t)pos * 96 + c] = 0;
    }
}

// ---------------- MFMA implicit-GEMM conv layer ----------------------------------------
// in : [b][d1][d2][d3][d4][CIN_S]  bf16
// wp : [81][CIN_S/8][COUT_C][8]    bf16 (B-fragment native)
// out: [b][d1][d2][d3][d4][COUT_STRIDE] bf16, channels 0..COUT_C-1 written
// Block = one (b,d1,d2) plane: M=256 positions. 4*WN waves; wave = 64 rows x NT*16 cols.
template<int CIN_S, int COUT_C, int COUT_STRIDE, int WN>
__global__ __launch_bounds__(256 * WN) void conv_mfma(
    const ushort* __restrict__ in, const ushort* __restrict__ wp,
    const float* __restrict__ bias, int cout_real, ushort* __restrict__ out)
{
    constexpr int NT = COUT_C / (16 * WN);
    constexpr int KC = CIN_S / 32;
    constexpr int TAPW = CIN_S * COUT_C;      // shorts per tap
    constexpr int NTHR = 256 * WN;
    __shared__ __attribute__((aligned(16))) ushort ws[2][TAPW];

    const int tid = threadIdx.x;
    const int lane = tid & 63;
    const int w = tid >> 6;
    const int wm = w / WN;          // 0..3  (d3 group)
    const int wn = w % WN;          // N half
    const int r = lane & 15;        // A-row (=d4) / B-col / D-col
    const int g = lane >> 4;        // k-group / D row-group

    const int bx = blockIdx.x;
    const int d2 = bx & 15, d1 = (bx >> 4) & 15, b = bx >> 8;

    const ushort* inb = in + (size_t)b * 65536 * CIN_S;
    const int co0 = wn * NT * 16;

    f32x4 acc[4][NT];
    #pragma unroll
    for (int f = 0; f < 4; ++f)
        #pragma unroll
        for (int n = 0; n < NT; ++n)
            acc[f][n] = (f32x4){0.f, 0.f, 0.f, 0.f};

    // stage tap 0 into buf 0
    {
        const short8* src = (const short8*)wp;
        short8* dst = (short8*)ws[0];
        for (int i = tid; i < TAPW / 8; i += NTHR) dst[i] = src[i];
    }

    for (int t = 0; t < 81; ++t){
        const int s = t & 1;
        __syncthreads();
        if (t < 80){   // prefetch next tap into other buffer
            const short8* src = (const short8*)(wp + (size_t)(t + 1) * TAPW);
            short8* dst = (short8*)ws[s ^ 1];
            for (int i = tid; i < TAPW / 8; i += NTHR) dst[i] = src[i];
        }
        const int t4 = t % 3, t3 = (t / 3) % 3, t2 = (t / 9) % 3, t1 = t / 27;
        const int e1 = d1 + t1 - 1, e2 = d2 + t2 - 1;
        if ((unsigned)e1 >= 16u || (unsigned)e2 >= 16u) continue;
        const int e4 = r + t4 - 1;
        const bool v4 = (unsigned)e4 < 16u;
        const ushort* pbase = inb + (size_t)((e1 * 16 + e2) * 256) * CIN_S;

        #pragma unroll
        for (int c = 0; c < KC; ++c){
            short8 bfr[NT];
            const ushort* wrow = ws[s] + ((size_t)(c * 4 + g) * COUT_C + co0 + r) * 8;
            #pragma unroll
            for (int n = 0; n < NT; ++n)
                bfr[n] = *(const short8*)(wrow + n * 128);
            #pragma unroll
            for (int f = 0; f < 4; ++f){
                const int e3 = wm * 4 + f + t3 - 1;
                if ((unsigned)e3 < 16u){
                    short8 af = {0, 0, 0, 0, 0, 0, 0, 0};
                    if (v4)
                        af = *(const short8*)(pbase + (size_t)(e3 * 16 + e4) * CIN_S + c * 32 + g * 8);
                    #pragma unroll
                    for (int n = 0; n < NT; ++n)
                        acc[f][n] = __builtin_amdgcn_mfma_f32_16x16x32_bf16(af, bfr[n], acc[f][n], 0, 0, 0);
                }
            }
        }
    }

    // epilogue: bias + ReLU + bf16 store
    float bv[NT];
    #pragma unroll
    for (int n = 0; n < NT; ++n){
        int co = co0 + n * 16 + r;
        bv[n] = (co < cout_real) ? bias[co] : 0.f;
    }
    ushort* ob = out + (size_t)bx * 256 * COUT_STRIDE;
    #pragma unroll
    for (int f = 0; f < 4; ++f){
        const int d3 = wm * 4 + f;
        #pragma unroll
        for (int n = 0; n < NT; ++n){
            const int co = co0 + n * 16 + r;
            #pragma unroll
            for (int j = 0; j < 4; ++j){
                const int d4 = g * 4 + j;
                float v = acc[f][n][j] + bv[n];
                v = v > 0.f ? v : 0.f;
                ob[(size_t)(d3 * 16 + d4) * COUT_STRIDE + co] = f2bf(v);
            }
        }
    }
}

extern "C" void kernel_launch(void* const* d_in, const int* in_sizes, int n_in,
                              void* d_out, int out_size, void* d_ws, size_t ws_size,
                              hipStream_t stream) {
    const float* x  = (const float*)d_in[0];
    const float* w1 = (const float*)d_in[1];  const float* b1 = (const float*)d_in[2];
    const float* w2 = (const float*)d_in[3];  const float* b2 = (const float*)d_in[4];
    const float* w3 = (const float*)d_in[5];  const float* b3 = (const float*)d_in[6];
    const float* w4 = (const float*)d_in[7];  const float* b4 = (const float*)d_in[8];
    const float* w5 = (const float*)d_in[9];  const float* b5 = (const float*)d_in[10];
    const float* w6 = (const float*)d_in[11]; const float* b6 = (const float*)d_in[12];

    // workspace layout (bf16 ushorts):
    ushort* bufA = (ushort*)d_ws;                       // [131072][160] max : 41.9 MB
    ushort* bufB = bufA + (size_t)131072 * 160;         // [131072][96]       : 25.2 MB
    ushort* wp2  = bufB + (size_t)131072 * 96;          // 81*64*80
    ushort* wp3  = wp2 + (size_t)81 * 64 * 80;          // 81*96*160
    ushort* wp4  = wp3 + (size_t)81 * 96 * 160;         // 81*160*80
    ushort* wp5  = wp4 + (size_t)81 * 160 * 80;         // 81*96*64

    repack_w<<<512, 256, 0, stream>>>(w2, wp2, 40, 80, 64, 80);
    repack_w<<<512, 256, 0, stream>>>(w3, wp3, 80, 160, 96, 160);
    repack_w<<<512, 256, 0, stream>>>(w4, wp4, 160, 80, 160, 80);
    repack_w<<<512, 256, 0, stream>>>(w5, wp5, 80, 40, 96, 64);
    fill_pad<<<8192, 256, 0, stream>>>(bufB);

    conv_l1<<<512, 256, 0, stream>>>(x, w1, b1, bufA);
    conv_mfma< 64,  80,  96, 1><<<512, 256, 0, stream>>>(bufA, wp2, b2, 80, bufB);
    conv_mfma< 96, 160, 160, 2><<<512, 512, 0, stream>>>(bufB, wp3, b3, 160, bufA);
    conv_mfma<160,  80,  96, 1><<<512, 256, 0, stream>>>(bufA, wp4, b4, 80, bufB);
    conv_mfma< 96,  64,  64, 1><<<512, 256, 0, stream>>>(bufB, wp5, b5, 40, bufA);
    conv_l6<<<512, 256, 0, stream>>>(bufA, w6, b6, (float*)d_out);
}

// Round 3
// 1743.887 us; speedup vs baseline: 25.0911x; 1.0515x over previous
//
#include <hip/hip_runtime.h>

typedef __attribute__((ext_vector_type(8))) short short8;
typedef __attribute__((ext_vector_type(4))) float f32x4;

__device__ __forceinline__ ushort f2bf(float f){
    union { float f; unsigned u; } v; v.f = f;
    unsigned r = (v.u + 0x7fffu + ((v.u >> 16) & 1u)) >> 16;
    return (ushort)r;
}
__device__ __forceinline__ float bf2f(ushort u){
    union { unsigned u; float f; } v; v.u = ((unsigned)u) << 16;
    return v.f;
}

// ---------------- Layer 1: Cin=1 -> 40 real (stored 64, pad zero), direct fp32 ----------
__global__ __launch_bounds__(256) void conv_l1(
    const float* __restrict__ x, const float* __restrict__ w,
    const float* __restrict__ bias, ushort* __restrict__ out)
{
    __shared__ float xs[2916];     // [3][3][18][18] padded neighborhood
    __shared__ float wsh[3240];    // [40][81]
    const int tid = threadIdx.x;
    const int bx = blockIdx.x;
    const int d2 = bx & 15, d1 = (bx >> 4) & 15, b = bx >> 8;
    const float* xb = x + (size_t)b * 65536;

    for (int i = tid; i < 2916; i += 256){
        int i4 = i % 18; int r1 = i / 18; int i3 = r1 % 18;
        int r2 = r1 / 18; int a2 = r2 % 3; int a1 = r2 / 3;
        int e1 = d1 + a1 - 1, e2 = d2 + a2 - 1, e3 = i3 - 1, e4 = i4 - 1;
        float v = 0.f;
        if ((unsigned)e1 < 16u && (unsigned)e2 < 16u && (unsigned)e3 < 16u && (unsigned)e4 < 16u)
            v = xb[((e1 * 16 + e2) * 16 + e3) * 16 + e4];
        xs[i] = v;
    }
    for (int i = tid; i < 3240; i += 256) wsh[i] = w[i];
    __syncthreads();

    const int d3 = tid >> 4, d4 = tid & 15;
    float acc[40];
    #pragma unroll
    for (int c = 0; c < 40; ++c) acc[c] = 0.f;

    for (int t1 = 0; t1 < 3; ++t1)
    for (int t2 = 0; t2 < 3; ++t2)
    for (int t3 = 0; t3 < 3; ++t3)
    #pragma unroll
    for (int t4 = 0; t4 < 3; ++t4){
        float xv = xs[((t1 * 3 + t2) * 18 + d3 + t3) * 18 + d4 + t4];
        int tap = ((t1 * 3 + t2) * 3 + t3) * 3 + t4;
        #pragma unroll
        for (int c = 0; c < 40; ++c) acc[c] += wsh[c * 81 + tap] * xv;
    }

    ushort* ob = out + ((size_t)bx * 256 + tid) * 64;
    #pragma unroll
    for (int c = 0; c < 40; ++c){
        float v = acc[c] + bias[c]; v = v > 0.f ? v : 0.f;
        ob[c] = f2bf(v);
    }
    #pragma unroll
    for (int c = 40; c < 64; ++c) ob[c] = 0;
}

// ---------------- Layer 6: 40 real (stored 64) -> Cout=1, direct fp32 -------------------
__global__ __launch_bounds__(256) void conv_l6(
    const ushort* __restrict__ in, const float* __restrict__ w,
    const float* __restrict__ bias, float* __restrict__ out)
{
    __shared__ float wsh[3240];    // [ci=40][81]
    const int tid = threadIdx.x;
    const int bx = blockIdx.x;
    const int d2 = bx & 15, d1 = (bx >> 4) & 15, b = bx >> 8;
    for (int i = tid; i < 3240; i += 256) wsh[i] = w[i];
    __syncthreads();

    const int d3 = tid >> 4, d4 = tid & 15;
    const ushort* inb = in + (size_t)b * 65536 * 64;
    float acc = 0.f;
    for (int t1 = 0; t1 < 3; ++t1){
        int e1 = d1 + t1 - 1; if ((unsigned)e1 >= 16u) continue;
        for (int t2 = 0; t2 < 3; ++t2){
            int e2 = d2 + t2 - 1; if ((unsigned)e2 >= 16u) continue;
            for (int t3 = 0; t3 < 3; ++t3){
                int e3 = d3 + t3 - 1; if ((unsigned)e3 >= 16u) continue;
                for (int t4 = 0; t4 < 3; ++t4){
                    int e4 = d4 + t4 - 1; if ((unsigned)e4 >= 16u) continue;
                    const ushort* p = inb + (size_t)(((e1 * 16 + e2) * 16 + e3) * 16 + e4) * 64;
                    int tap = ((t1 * 3 + t2) * 3 + t3) * 3 + t4;
                    #pragma unroll
                    for (int c8 = 0; c8 < 5; ++c8){
                        short8 v = *(const short8*)(p + c8 * 8);
                        #pragma unroll
                        for (int j = 0; j < 8; ++j)
                            acc += bf2f((ushort)v[j]) * wsh[(c8 * 8 + j) * 81 + tap];
                    }
                }
            }
        }
    }
    float v = acc + bias[0]; v = v > 0.f ? v : 0.f;
    out[(size_t)bx * 256 + tid] = v;
}

// ---------------- Weight repack: [co][ci][81] fp32 -> [81][ci/8][co][8] bf16 ------------
__global__ void repack_w(const float* __restrict__ w, ushort* __restrict__ wp,
                         int cin, int cout, int cin_s, int cout_c)
{
    const int total = 81 * cin_s * cout_c;
    for (int i = blockIdx.x * blockDim.x + threadIdx.x; i < total; i += gridDim.x * blockDim.x){
        int j = i & 7;
        int rest = i >> 3;
        int co = rest % cout_c;
        int rest2 = rest / cout_c;
        int ci_hi = rest2 % (cin_s >> 3);
        int t = rest2 / (cin_s >> 3);
        int ci = ci_hi * 8 + j;
        float v = (ci < cin && co < cout) ? w[((size_t)co * cin + ci) * 81 + t] : 0.f;
        wp[i] = f2bf(v);
    }
}

// ---------------- MFMA implicit-GEMM conv layer ----------------------------------------
// in : [b][d1][d2][d3][d4][CIN_S]  bf16
// wp : [81][CIN_S/8][COUT_C][8]    bf16 (B-fragment native)
// out: [b][d1][d2][d3][d4][COUT_C] bf16 (pad channels written as 0 via zero weights)
// Block = one (b,d1,d2) plane: M=256 positions. 8 waves = 4 M-waves x 2 N-waves.
// XCD-aware swizzle: 64 consecutive logical blocks (4x16 d1,d2 panel) per XCD.
template<int CIN_S, int COUT_C>
__global__ __launch_bounds__(512) void conv_mfma(
    const ushort* __restrict__ in, const ushort* __restrict__ wp,
    const float* __restrict__ bias, int cout_real, ushort* __restrict__ out)
{
    constexpr int NT = COUT_C / 32;           // WN = 2
    constexpr int KC = CIN_S / 32;
    constexpr int TAPW = CIN_S * COUT_C;      // shorts per tap
    __shared__ __attribute__((aligned(16))) ushort ws[2][TAPW];

    const int tid = threadIdx.x;
    const int lane = tid & 63;
    const int w = tid >> 6;
    const int wm = w >> 1;          // 0..3  (d3 group)
    const int wn = w & 1;           // N half
    const int r = lane & 15;        // A-row (=d4) / B-col / D-col
    const int g = lane >> 4;        // k-group / D row-group

    // XCD-aware chunked swizzle (grid=512, 8 XCDs, 64 blocks/XCD-chunk)
    const int p = blockIdx.x;
    const int bx = (p & 7) * 64 + (p >> 3);
    const int d2 = bx & 15, d1 = (bx >> 4) & 15, b = bx >> 8;

    const ushort* inb = in + (size_t)b * 65536 * CIN_S;
    const int co0 = wn * NT * 16;

    f32x4 acc[4][NT];
    #pragma unroll
    for (int f = 0; f < 4; ++f)
        #pragma unroll
        for (int n = 0; n < NT; ++n)
            acc[f][n] = (f32x4){0.f, 0.f, 0.f, 0.f};

    // stage tap 0 into buf 0
    {
        const short8* src = (const short8*)wp;
        short8* dst = (short8*)ws[0];
        for (int i = tid; i < TAPW / 8; i += 512) dst[i] = src[i];
    }

    for (int t = 0; t < 81; ++t){
        const int s = t & 1;
        __syncthreads();
        if (t < 80){   // prefetch next tap into other buffer
            const short8* src = (const short8*)(wp + (size_t)(t + 1) * TAPW);
            short8* dst = (short8*)ws[s ^ 1];
            for (int i = tid; i < TAPW / 8; i += 512) dst[i] = src[i];
        }
        const int t4 = t % 3, t3 = (t / 3) % 3, t2 = (t / 9) % 3, t1 = t / 27;
        const int e1 = d1 + t1 - 1, e2 = d2 + t2 - 1;
        if ((unsigned)e1 >= 16u || (unsigned)e2 >= 16u) continue;
        const int e4 = r + t4 - 1;
        const bool v4 = (unsigned)e4 < 16u;
        const ushort* pbase = inb + (size_t)((e1 * 16 + e2) * 256) * CIN_S;

        #pragma unroll
        for (int c = 0; c < KC; ++c){
            short8 bfr[NT];
            const ushort* wrow = ws[s] + ((size_t)(c * 4 + g) * COUT_C + co0 + r) * 8;
            #pragma unroll
            for (int n = 0; n < NT; ++n)
                bfr[n] = *(const short8*)(wrow + n * 128);
            #pragma unroll
            for (int f = 0; f < 4; ++f){
                const int e3 = wm * 4 + f + t3 - 1;
                if ((unsigned)e3 < 16u){
                    short8 af = {0, 0, 0, 0, 0, 0, 0, 0};
                    if (v4)
                        af = *(const short8*)(pbase + (size_t)(e3 * 16 + e4) * CIN_S + c * 32 + g * 8);
                    #pragma unroll
                    for (int n = 0; n < NT; ++n)
                        acc[f][n] = __builtin_amdgcn_mfma_f32_16x16x32_bf16(af, bfr[n], acc[f][n], 0, 0, 0);
                }
            }
        }
    }

    // epilogue: bias + ReLU + bf16 store
    float bv[NT];
    #pragma unroll
    for (int n = 0; n < NT; ++n){
        int co = co0 + n * 16 + r;
        bv[n] = (co < cout_real) ? bias[co] : 0.f;
    }
    ushort* ob = out + (size_t)bx * 256 * COUT_C;
    #pragma unroll
    for (int f = 0; f < 4; ++f){
        const int d3 = wm * 4 + f;
        #pragma unroll
        for (int n = 0; n < NT; ++n){
            const int co = co0 + n * 16 + r;
            #pragma unroll
            for (int j = 0; j < 4; ++j){
                const int d4 = g * 4 + j;
                float v = acc[f][n][j] + bv[n];
                v = v > 0.f ? v : 0.f;
                ob[(size_t)(d3 * 16 + d4) * COUT_C + co] = f2bf(v);
            }
        }
    }
}

extern "C" void kernel_launch(void* const* d_in, const int* in_sizes, int n_in,
                              void* d_out, int out_size, void* d_ws, size_t ws_size,
                              hipStream_t stream) {
    const float* x  = (const float*)d_in[0];
    const float* w1 = (const float*)d_in[1];  const float* b1 = (const float*)d_in[2];
    const float* w2 = (const float*)d_in[3];  const float* b2 = (const float*)d_in[4];
    const float* w3 = (const float*)d_in[5];  const float* b3 = (const float*)d_in[6];
    const float* w4 = (const float*)d_in[7];  const float* b4 = (const float*)d_in[8];
    const float* w5 = (const float*)d_in[9];  const float* b5 = (const float*)d_in[10];
    const float* w6 = (const float*)d_in[11]; const float* b6 = (const float*)d_in[12];

    // workspace layout (bf16 ushorts):
    ushort* bufA = (ushort*)d_ws;                       // [131072][160] : 41.9 MB
    ushort* bufB = bufA + (size_t)131072 * 160;         // [131072][96]  : 25.2 MB
    ushort* wp2  = bufB + (size_t)131072 * 96;          // 81*64*96
    ushort* wp3  = wp2 + (size_t)81 * 64 * 96;          // 81*96*160
    ushort* wp4  = wp3 + (size_t)81 * 96 * 160;         // 81*160*96
    ushort* wp5  = wp4 + (size_t)81 * 160 * 96;         // 81*96*64

    repack_w<<<512, 256, 0, stream>>>(w2, wp2, 40, 80, 64, 96);
    repack_w<<<512, 256, 0, stream>>>(w3, wp3, 80, 160, 96, 160);
    repack_w<<<512, 256, 0, stream>>>(w4, wp4, 160, 80, 160, 96);
    repack_w<<<512, 256, 0, stream>>>(w5, wp5, 80, 40, 96, 64);

    conv_l1<<<512, 256, 0, stream>>>(x, w1, b1, bufA);
    conv_mfma< 64,  96><<<512, 512, 0, stream>>>(bufA, wp2, b2, 80, bufB);
    conv_mfma< 96, 160><<<512, 512, 0, stream>>>(bufB, wp3, b3, 160, bufA);
    conv_mfma<160,  96><<<512, 512, 0, stream>>>(bufA, wp4, b4, 80, bufB);
    conv_mfma< 96,  64><<<512, 512, 0, stream>>>(bufB, wp5, b5, 40, bufA);
    conv_l6<<<512, 256, 0, stream>>>(bufA, w6, b6, (float*)d_out);
}

// Round 4
// 1120.088 us; speedup vs baseline: 39.0648x; 1.5569x over previous
//
#include <hip/hip_runtime.h>

typedef __attribute__((ext_vector_type(8))) short short8;
typedef __attribute__((ext_vector_type(4))) float f32x4;

__device__ __forceinline__ ushort f2bf(float f){
    union { float f; unsigned u; } v; v.f = f;
    unsigned r = (v.u + 0x7fffu + ((v.u >> 16) & 1u)) >> 16;
    return (ushort)r;
}
__device__ __forceinline__ float bf2f(ushort u){
    union { unsigned u; float f; } v; v.u = ((unsigned)u) << 16;
    return v.f;
}

// ---------------- Layer 1: Cin=1 -> 40 real (stored 64, pad zero), direct fp32 ----------
__global__ __launch_bounds__(256) void conv_l1(
    const float* __restrict__ x, const float* __restrict__ w,
    const float* __restrict__ bias, ushort* __restrict__ out)
{
    __shared__ float xs[2916];     // [3][3][18][18] padded neighborhood
    __shared__ float wsh[3240];    // [40][81]
    const int tid = threadIdx.x;
    const int bx = blockIdx.x;
    const int d2 = bx & 15, d1 = (bx >> 4) & 15, b = bx >> 8;
    const float* xb = x + (size_t)b * 65536;

    for (int i = tid; i < 2916; i += 256){
        int i4 = i % 18; int r1 = i / 18; int i3 = r1 % 18;
        int r2 = r1 / 18; int a2 = r2 % 3; int a1 = r2 / 3;
        int e1 = d1 + a1 - 1, e2 = d2 + a2 - 1, e3 = i3 - 1, e4 = i4 - 1;
        float v = 0.f;
        if ((unsigned)e1 < 16u && (unsigned)e2 < 16u && (unsigned)e3 < 16u && (unsigned)e4 < 16u)
            v = xb[((e1 * 16 + e2) * 16 + e3) * 16 + e4];
        xs[i] = v;
    }
    for (int i = tid; i < 3240; i += 256) wsh[i] = w[i];
    __syncthreads();

    const int d3 = tid >> 4, d4 = tid & 15;
    float acc[40];
    #pragma unroll
    for (int c = 0; c < 40; ++c) acc[c] = 0.f;

    for (int t1 = 0; t1 < 3; ++t1)
    for (int t2 = 0; t2 < 3; ++t2)
    for (int t3 = 0; t3 < 3; ++t3)
    #pragma unroll
    for (int t4 = 0; t4 < 3; ++t4){
        float xv = xs[((t1 * 3 + t2) * 18 + d3 + t3) * 18 + d4 + t4];
        int tap = ((t1 * 3 + t2) * 3 + t3) * 3 + t4;
        #pragma unroll
        for (int c = 0; c < 40; ++c) acc[c] += wsh[c * 81 + tap] * xv;
    }

    ushort* ob = out + ((size_t)bx * 256 + tid) * 64;
    #pragma unroll
    for (int c = 0; c < 40; ++c){
        float v = acc[c] + bias[c]; v = v > 0.f ? v : 0.f;
        ob[c] = f2bf(v);
    }
    #pragma unroll
    for (int c = 40; c < 64; ++c) ob[c] = 0;
}

// ---------------- Layer 6: 40 real (stored 64) -> Cout=1, direct fp32 -------------------
__global__ __launch_bounds__(256) void conv_l6(
    const ushort* __restrict__ in, const float* __restrict__ w,
    const float* __restrict__ bias, float* __restrict__ out)
{
    __shared__ float wsh[3240];    // [ci=40][81]
    const int tid = threadIdx.x;
    const int bx = blockIdx.x;
    const int d2 = bx & 15, d1 = (bx >> 4) & 15, b = bx >> 8;
    for (int i = tid; i < 3240; i += 256) wsh[i] = w[i];
    __syncthreads();

    const int d3 = tid >> 4, d4 = tid & 15;
    const ushort* inb = in + (size_t)b * 65536 * 64;
    float acc = 0.f;
    for (int t1 = 0; t1 < 3; ++t1){
        int e1 = d1 + t1 - 1; if ((unsigned)e1 >= 16u) continue;
        for (int t2 = 0; t2 < 3; ++t2){
            int e2 = d2 + t2 - 1; if ((unsigned)e2 >= 16u) continue;
            for (int t3 = 0; t3 < 3; ++t3){
                int e3 = d3 + t3 - 1; if ((unsigned)e3 >= 16u) continue;
                for (int t4 = 0; t4 < 3; ++t4){
                    int e4 = d4 + t4 - 1; if ((unsigned)e4 >= 16u) continue;
                    const ushort* p = inb + (size_t)(((e1 * 16 + e2) * 16 + e3) * 16 + e4) * 64;
                    int tap = ((t1 * 3 + t2) * 3 + t3) * 3 + t4;
                    #pragma unroll
                    for (int c8 = 0; c8 < 5; ++c8){
                        short8 v = *(const short8*)(p + c8 * 8);
                        #pragma unroll
                        for (int j = 0; j < 8; ++j)
                            acc += bf2f((ushort)v[j]) * wsh[(c8 * 8 + j) * 81 + tap];
                    }
                }
            }
        }
    }
    float v = acc + bias[0]; v = v > 0.f ? v : 0.f;
    out[(size_t)bx * 256 + tid] = v;
}

// ---------------- Weight repack: [co][ci][81] fp32 -> [81][ci/8][co][8] bf16 ------------
__global__ void repack_w(const float* __restrict__ w, ushort* __restrict__ wp,
                         int cin, int cout, int cin_s, int cout_c)
{
    const int total = 81 * cin_s * cout_c;
    for (int i = blockIdx.x * blockDim.x + threadIdx.x; i < total; i += gridDim.x * blockDim.x){
        int j = i & 7;
        int rest = i >> 3;
        int co = rest % cout_c;
        int rest2 = rest / cout_c;
        int ci_hi = rest2 % (cin_s >> 3);
        int t = rest2 / (cin_s >> 3);
        int ci = ci_hi * 8 + j;
        float v = (ci < cin && co < cout) ? w[((size_t)co * cin + ci) * 81 + t] : 0.f;
        wp[i] = f2bf(v);
    }
}

// ---------------- MFMA implicit-GEMM conv layer, all operands LDS-staged ----------------
// in : [b][d1][d2][d3][d4][CIN_S]  bf16
// wp : [81][ci/8][COUT_C][8]       bf16 (B-fragment native)
// out: [b][d1][d2][d3][d4][COUT_C] bf16
// Loop: (t1,t2) group -> kh (32-ch K-chunk) -> 9 (t3,t4) taps.
// A-chunk [256 pos][32ch->40 pad] staged per (group,kh), dbuf, prefetch dist 9 steps.
// B-chunk [32ch][COUT_C] staged per step, dbuf, prefetch dist 1 step.
template<int CIN_S, int COUT_C>
__global__ __launch_bounds__(512, 4) void conv_mfma(
    const ushort* __restrict__ in, const ushort* __restrict__ wp,
    const float* __restrict__ bias, int cout_real, ushort* __restrict__ out)
{
    constexpr int KH = CIN_S / 32;            // K-chunks
    constexpr int NT = COUT_C / 32;           // N tiles per wave (wn=2)
    constexpr int NPASS = 9 * KH;             // (group,kh) passes
    constexpr int ACH = 256 * 40;             // shorts per A buffer (padded 32->40 ch)
    constexpr int BCH = 32 * COUT_C;          // shorts per B chunk

    __shared__ __attribute__((aligned(16))) ushort As[2][ACH];
    __shared__ __attribute__((aligned(16))) ushort Bs[2][BCH];

    const int tid = threadIdx.x;
    const int lane = tid & 63;
    const int w = tid >> 6;
    const int wm = w >> 1;          // 0..3 (d3 group)
    const int wn = w & 1;           // N half
    const int r = lane & 15;        // A-row (=d4) / B-col / D-col
    const int g = lane >> 4;        // k-group / D row-group

    // XCD-aware chunked swizzle (grid=512, 8 XCDs, 64 blocks/XCD-chunk)
    const int p0 = blockIdx.x;
    const int bx = (p0 & 7) * 64 + (p0 >> 3);
    const int d2 = bx & 15, d1 = (bx >> 4) & 15, b = bx >> 8;

    const ushort* inb = in + (size_t)b * 65536 * CIN_S;
    const int co0 = wn * NT * 16;

    f32x4 acc[4][NT];
    #pragma unroll
    for (int f = 0; f < 4; ++f)
        #pragma unroll
        for (int n = 0; n < NT; ++n)
            acc[f][n] = (f32x4){0.f, 0.f, 0.f, 0.f};

    auto stageA = [&](int p, ushort* dst) {
        const int gg = p / KH, kh = p % KH;
        const int t1 = gg / 3, t2 = gg % 3;
        const int e1 = d1 + t1 - 1, e2 = d2 + t2 - 1;
        if ((unsigned)e1 >= 16u || (unsigned)e2 >= 16u) return;  // group skipped entirely
        const ushort* src = inb + ((size_t)(e1 * 16 + e2) * 256) * CIN_S + kh * 32;
        for (int i = tid; i < 1024; i += 512) {
            const int pos = i >> 2, ck = (i & 3) * 8;
            *(short8*)(dst + pos * 40 + ck) = *(const short8*)(src + (size_t)pos * CIN_S + ck);
        }
    };
    auto stageB = [&](int sg, ushort* dst) {
        const int pp = sg / 9, tt = sg % 9;
        const int tap = (pp / KH) * 9 + tt, kh = pp % KH;
        const short8* s8 = (const short8*)(wp + (size_t)tap * (CIN_S * COUT_C) + kh * BCH);
        short8* d8 = (short8*)dst;
        for (int i = tid; i < BCH / 8; i += 512) d8[i] = s8[i];
    };

    stageA(0, As[0]);
    stageB(0, Bs[0]);

    for (int p = 0; p < NPASS; ++p) {
        const int gg = p / KH;
        const int t1 = gg / 3, t2 = gg % 3;
        const bool gvalid = ((unsigned)(d1 + t1 - 1) < 16u) && ((unsigned)(d2 + t2 - 1) < 16u);
        const int sA = p & 1;
        for (int tt = 0; tt < 9; ++tt) {
            const int sg = p * 9 + tt;
            const int sB = sg & 1;
            __syncthreads();
            if (tt == 0 && p + 1 < NPASS) stageA(p + 1, As[sA ^ 1]);
            if (sg + 1 < NPASS * 9) stageB(sg + 1, Bs[sB ^ 1]);
            if (!gvalid) continue;

            const int t3 = tt / 3, t4 = tt % 3;
            const int e4 = r + t4 - 1;
            const bool v4 = (unsigned)e4 < 16u;

            short8 bfr[NT];
            #pragma unroll
            for (int n = 0; n < NT; ++n)
                bfr[n] = *(const short8*)(Bs[sB] + (g * COUT_C + co0 + n * 16 + r) * 8);

            #pragma unroll
            for (int f = 0; f < 4; ++f) {
                const int e3 = wm * 4 + f + t3 - 1;
                if ((unsigned)e3 < 16u) {
                    short8 af = {0, 0, 0, 0, 0, 0, 0, 0};
                    if (v4)
                        af = *(const short8*)(As[sA] + (e3 * 16 + e4) * 40 + g * 8);
                    #pragma unroll
                    for (int n = 0; n < NT; ++n)
                        acc[f][n] = __builtin_amdgcn_mfma_f32_16x16x32_bf16(af, bfr[n], acc[f][n], 0, 0, 0);
                }
            }
        }
    }

    // epilogue: bias + ReLU + bf16 store
    float bv[NT];
    #pragma unroll
    for (int n = 0; n < NT; ++n){
        int co = co0 + n * 16 + r;
        bv[n] = (co < cout_real) ? bias[co] : 0.f;
    }
    ushort* ob = out + (size_t)bx * 256 * COUT_C;
    #pragma unroll
    for (int f = 0; f < 4; ++f){
        const int d3 = wm * 4 + f;
        #pragma unroll
        for (int n = 0; n < NT; ++n){
            const int co = co0 + n * 16 + r;
            #pragma unroll
            for (int j = 0; j < 4; ++j){
                const int d4 = g * 4 + j;
                float v = acc[f][n][j] + bv[n];
                v = v > 0.f ? v : 0.f;
                ob[(size_t)(d3 * 16 + d4) * COUT_C + co] = f2bf(v);
            }
        }
    }
}

extern "C" void kernel_launch(void* const* d_in, const int* in_sizes, int n_in,
                              void* d_out, int out_size, void* d_ws, size_t ws_size,
                              hipStream_t stream) {
    const float* x  = (const float*)d_in[0];
    const float* w1 = (const float*)d_in[1];  const float* b1 = (const float*)d_in[2];
    const float* w2 = (const float*)d_in[3];  const float* b2 = (const float*)d_in[4];
    const float* w3 = (const float*)d_in[5];  const float* b3 = (const float*)d_in[6];
    const float* w4 = (const float*)d_in[7];  const float* b4 = (const float*)d_in[8];
    const float* w5 = (const float*)d_in[9];  const float* b5 = (const float*)d_in[10];
    const float* w6 = (const float*)d_in[11]; const float* b6 = (const float*)d_in[12];

    // workspace layout (bf16 ushorts):
    ushort* bufA = (ushort*)d_ws;                       // [131072][160] : 41.9 MB
    ushort* bufB = bufA + (size_t)131072 * 160;         // [131072][96]  : 25.2 MB
    ushort* wp2  = bufB + (size_t)131072 * 96;          // 81*64*96
    ushort* wp3  = wp2 + (size_t)81 * 64 * 96;          // 81*96*160
    ushort* wp4  = wp3 + (size_t)81 * 96 * 160;         // 81*160*96
    ushort* wp5  = wp4 + (size_t)81 * 160 * 96;         // 81*96*64

    repack_w<<<512, 256, 0, stream>>>(w2, wp2, 40, 80, 64, 96);
    repack_w<<<512, 256, 0, stream>>>(w3, wp3, 80, 160, 96, 160);
    repack_w<<<512, 256, 0, stream>>>(w4, wp4, 160, 80, 160, 96);
    repack_w<<<512, 256, 0, stream>>>(w5, wp5, 80, 40, 96, 64);

    conv_l1<<<512, 256, 0, stream>>>(x, w1, b1, bufA);
    conv_mfma< 64,  96><<<512, 512, 0, stream>>>(bufA, wp2, b2, 80, bufB);
    conv_mfma< 96, 160><<<512, 512, 0, stream>>>(bufB, wp3, b3, 160, bufA);
    conv_mfma<160,  96><<<512, 512, 0, stream>>>(bufA, wp4, b4, 80, bufB);
    conv_mfma< 96,  64><<<512, 512, 0, stream>>>(bufB, wp5, b5, 40, bufA);
    conv_l6<<<512, 256, 0, stream>>>(bufA, w6, b6, (float*)d_out);
}